// Round 1
// baseline (5194.231 us; speedup 1.0000x reference)
//
#include <hip/hip_runtime.h>
#include <math.h>

#define NB 4096
#define NT 256
#define ND 8
#define NH 64

// ---------------------------------------------------------------------------
// ws layout (floats):
//   P_hh0 : [64][256]  @ 0       (P[m][4j+k] = Whh0[j+64k][m])
//   P_ih1 : [64][256]  @ 16384
//   P_hh1 : [64][256]  @ 32768
//   P_ih0 : [ 9][256]  @ 49152
//   P_w1  : [ 9][64]   @ 51456   (P[m][j] = W1[j][m])
//   bs0   : [256]      @ 52032   (bs0[4j+k] = bih0[j+64k]+bhh0[j+64k])
//   bs1   : [256]      @ 52288
// total 52544 floats = 210176 bytes
// ---------------------------------------------------------------------------

__device__ __forceinline__ float fexp2(float x) { return __builtin_amdgcn_exp2f(x); }
__device__ __forceinline__ float frcp(float x)  { return __builtin_amdgcn_rcpf(x); }
__device__ __forceinline__ float sigm(float x)  { return frcp(1.0f + fexp2(-1.44269504f * x)); }
__device__ __forceinline__ float tanh_(float x) { return fmaf(2.0f, frcp(1.0f + fexp2(-2.88539008f * x)), -1.0f); }

__global__ void prep_kernel(const float* __restrict__ W1,
                            const float* __restrict__ Wih0,
                            const float* __restrict__ Whh0,
                            const float* __restrict__ bih0,
                            const float* __restrict__ bhh0,
                            const float* __restrict__ Wih1,
                            const float* __restrict__ Whh1,
                            const float* __restrict__ bih1,
                            const float* __restrict__ bhh1,
                            float* __restrict__ ws)
{
    int tid = blockIdx.x * 256 + threadIdx.x;
    if (tid < 16384) {
        int m = tid >> 8, q = tid & 255;
        int j = q >> 2, k = q & 3, r = j + 64 * k;
        ws[tid]         = Whh0[r * 64 + m];
        ws[16384 + tid] = Wih1[r * 64 + m];
        ws[32768 + tid] = Whh1[r * 64 + m];
        if (m < 9) ws[49152 + m * 256 + q] = Wih0[r * 9 + m];
    }
    if (tid < 576) {
        int m = tid / 64, j = tid % 64;
        ws[51456 + tid] = W1[j * 9 + m];
    }
    if (tid < 256) {
        int j = tid >> 2, k = tid & 3, r = j + 64 * k;
        ws[52032 + tid] = bih0[r] + bhh0[r];
        ws[52288 + tid] = bih1[r] + bhh1[r];
    }
}

// a_k[b] += w4[k] * hv[b]
#define FMA16(w4, hv)                                                          \
    a0[0] = fmaf(w4.x, hv.x, a0[0]); a0[1] = fmaf(w4.x, hv.y, a0[1]);          \
    a0[2] = fmaf(w4.x, hv.z, a0[2]); a0[3] = fmaf(w4.x, hv.w, a0[3]);          \
    a1[0] = fmaf(w4.y, hv.x, a1[0]); a1[1] = fmaf(w4.y, hv.y, a1[1]);          \
    a1[2] = fmaf(w4.y, hv.z, a1[2]); a1[3] = fmaf(w4.y, hv.w, a1[3]);          \
    a2[0] = fmaf(w4.z, hv.x, a2[0]); a2[1] = fmaf(w4.z, hv.y, a2[1]);          \
    a2[2] = fmaf(w4.z, hv.z, a2[2]); a2[3] = fmaf(w4.z, hv.w, a2[3]);          \
    a3[0] = fmaf(w4.w, hv.x, a3[0]); a3[1] = fmaf(w4.w, hv.y, a3[1]);          \
    a3[2] = fmaf(w4.w, hv.z, a3[2]); a3[3] = fmaf(w4.w, hv.w, a3[3]);

// 4 waves / block, each wave independently owns 4 batch elements.
// No __syncthreads needed: every LDS region is private to one wave and the
// DS pipe is in-order within a wave (standard wave-synchronous LDS use).
__global__ __launch_bounds__(256)
void tft_main(const float* __restrict__ feat,   // (B,T,8)
              const float* __restrict__ W2,     // (9,64) row-major
              const float* __restrict__ b1,     // (64)
              const float* __restrict__ b2,     // (9)
              const float* __restrict__ Wo,     // (64)
              const float* __restrict__ bo,     // (1)
              const float* __restrict__ ws,
              float* __restrict__ out)          // (B,T)
{
    const int lane = threadIdx.x & 63;
    const int wv   = threadIdx.x >> 6;
    const int b0   = (blockIdx.x * 4 + wv) * 4;   // batch base for this wave

    // per-wave LDS slice: 928 floats (16B-aligned regions)
    __shared__ float lds[4 * 928];
    float* S = lds + wv * 928;
    const int XB = 0, XT = 48, LG = 96, HID = 144, H0 = 400, H1 = 656;

    const float* Phh0 = ws;
    const float* Pih1 = ws + 16384;
    const float* Phh1 = ws + 32768;
    const float* Pih0 = ws + 49152;
    const float* Pw1  = ws + 51456;

    const float4 bs0 = *(const float4*)(ws + 52032 + 4 * lane);
    const float4 bs1 = *(const float4*)(ws + 52288 + 4 * lane);
    const float b1v = b1[lane];
    const float wov = Wo[lane];
    const float bov = bo[0];

    // init state: h0 = h1 = 0 in LDS, c0 = c1 = 0 in regs, prev_delta = 0
    *(float4*)(S + H0 + 4 * lane) = float4{0.f, 0.f, 0.f, 0.f};
    *(float4*)(S + H1 + 4 * lane) = float4{0.f, 0.f, 0.f, 0.f};
    if (lane == 0) *(float4*)(S + XB + 32) = float4{0.f, 0.f, 0.f, 0.f};
    float c0[4] = {0.f, 0.f, 0.f, 0.f};
    float c1[4] = {0.f, 0.f, 0.f, 0.f};
    __syncthreads();   // one-time; waves independent afterwards

    for (int t = 0; t < NT; ++t) {
        // ---- phase 1: load x_t into XB[m][b], m<8 (XB[8][b] = prev_delta)
        if (lane < 32) {
            int b = lane >> 3, d = lane & 7;
            S[XB + d * 4 + b] = feat[((b0 + b) * NT + t) * ND + d];
        }

        // ---- phase 2: hid[j][b] = relu(b1[j] + sum_m W1[j][m] * x[m][b])
        {
            float hv[4] = {b1v, b1v, b1v, b1v};
            #pragma unroll
            for (int m = 0; m < 9; ++m) {
                float w = Pw1[m * 64 + lane];
                float4 xv = *(const float4*)(S + XB + m * 4);
                hv[0] = fmaf(w, xv.x, hv[0]);
                hv[1] = fmaf(w, xv.y, hv[1]);
                hv[2] = fmaf(w, xv.z, hv[2]);
                hv[3] = fmaf(w, xv.w, hv[3]);
            }
            float4 o;
            o.x = fmaxf(hv[0], 0.f); o.y = fmaxf(hv[1], 0.f);
            o.z = fmaxf(hv[2], 0.f); o.w = fmaxf(hv[3], 0.f);
            *(float4*)(S + HID + 4 * lane) = o;
        }

        // ---- phase 3: logits[r][b] = b2[r] + sum_m W2[r][m] * hid[m][b]
        if (lane < 36) {
            int bb = lane / 9, r = lane % 9;
            float acc = b2[r];
            #pragma unroll 8
            for (int m = 0; m < 64; ++m)
                acc = fmaf(W2[r * 64 + m], S[HID + m * 4 + bb], acc);
            S[LG + r * 4 + bb] = acc;
        }

        // ---- phase 4: softmax over r=0..8, x~ = x * w   (one lane per batch)
        if (lane < 4) {
            float lg[9];
            float mx = -1e30f;
            #pragma unroll
            for (int r = 0; r < 9; ++r) {
                lg[r] = S[LG + r * 4 + lane];
                mx = fmaxf(mx, lg[r]);
            }
            float sum = 0.f;
            #pragma unroll
            for (int r = 0; r < 9; ++r) {
                lg[r] = fexp2(1.44269504f * (lg[r] - mx));
                sum += lg[r];
            }
            float inv = frcp(sum);
            #pragma unroll
            for (int r = 0; r < 9; ++r)
                S[XT + r * 4 + lane] = S[XB + r * 4 + lane] * lg[r] * inv;
        }

        // ---- phase 5: LSTM layer 0. lane j owns gate rows j+64k (k=i,f,g,o)
        float a0[4], a1[4], a2[4], a3[4];
        #pragma unroll
        for (int b = 0; b < 4; ++b) { a0[b] = bs0.x; a1[b] = bs0.y; a2[b] = bs0.z; a3[b] = bs0.w; }
        #pragma unroll
        for (int m = 0; m < 9; ++m) {
            float4 w4 = *(const float4*)(Pih0 + m * 256 + 4 * lane);
            float4 xv = *(const float4*)(S + XT + 4 * m);
            FMA16(w4, xv)
        }
        #pragma unroll 8
        for (int m = 0; m < 64; ++m) {
            float4 w4 = *(const float4*)(Phh0 + m * 256 + 4 * lane);
            float4 hv = *(const float4*)(S + H0 + 4 * m);
            FMA16(w4, hv)
        }
        float h0n[4];
        #pragma unroll
        for (int b = 0; b < 4; ++b) {
            float i = sigm(a0[b]);
            float f = sigm(a1[b]);
            float g = tanh_(a2[b]);
            float o = sigm(a3[b]);
            c0[b] = f * c0[b] + i * g;
            h0n[b] = o * tanh_(c0[b]);
        }
        *(float4*)(S + H0 + 4 * lane) = float4{h0n[0], h0n[1], h0n[2], h0n[3]};

        // ---- phase 6: LSTM layer 1 (inputs: h0 new, h1 old)
        #pragma unroll
        for (int b = 0; b < 4; ++b) { a0[b] = bs1.x; a1[b] = bs1.y; a2[b] = bs1.z; a3[b] = bs1.w; }
        #pragma unroll 4
        for (int m = 0; m < 64; ++m) {
            float4 wA = *(const float4*)(Pih1 + m * 256 + 4 * lane);
            float4 hA = *(const float4*)(S + H0 + 4 * m);
            FMA16(wA, hA)
            float4 wB = *(const float4*)(Phh1 + m * 256 + 4 * lane);
            float4 hB = *(const float4*)(S + H1 + 4 * m);
            FMA16(wB, hB)
        }
        float h1n[4];
        #pragma unroll
        for (int b = 0; b < 4; ++b) {
            float i = sigm(a0[b]);
            float f = sigm(a1[b]);
            float g = tanh_(a2[b]);
            float o = sigm(a3[b]);
            c1[b] = f * c1[b] + i * g;
            h1n[b] = o * tanh_(c1[b]);
        }
        *(float4*)(S + H1 + 4 * lane) = float4{h1n[0], h1n[1], h1n[2], h1n[3]};

        // ---- phase 7: delta[b] = sum_j Wo[j]*h1[b][j] + bo  (butterfly)
        float v0 = wov * h1n[0];
        float v1 = wov * h1n[1];
        float v2 = wov * h1n[2];
        float v3 = wov * h1n[3];
        #pragma unroll
        for (int mask = 1; mask < 64; mask <<= 1) {
            v0 += __shfl_xor(v0, mask, 64);
            v1 += __shfl_xor(v1, mask, 64);
            v2 += __shfl_xor(v2, mask, 64);
            v3 += __shfl_xor(v3, mask, 64);
        }
        if (lane < 4) {
            float d = (lane == 0) ? v0 : (lane == 1) ? v1 : (lane == 2) ? v2 : v3;
            out[(b0 + lane) * NT + t] = d + bov;
        }
        if (lane == 0)   // feed back prev_delta for next step
            *(float4*)(S + XB + 32) = float4{v0 + bov, v1 + bov, v2 + bov, v3 + bov};
    }
}

extern "C" void kernel_launch(void* const* d_in, const int* in_sizes, int n_in,
                              void* d_out, int out_size, void* d_ws, size_t ws_size,
                              hipStream_t stream) {
    const float* feat = (const float*)d_in[0];
    const float* W1   = (const float*)d_in[1];
    const float* b1   = (const float*)d_in[2];
    const float* W2   = (const float*)d_in[3];
    const float* b2   = (const float*)d_in[4];
    const float* Wih0 = (const float*)d_in[5];
    const float* Whh0 = (const float*)d_in[6];
    const float* bih0 = (const float*)d_in[7];
    const float* bhh0 = (const float*)d_in[8];
    const float* Wih1 = (const float*)d_in[9];
    const float* Whh1 = (const float*)d_in[10];
    const float* bih1 = (const float*)d_in[11];
    const float* bhh1 = (const float*)d_in[12];
    const float* Wo   = (const float*)d_in[13];
    const float* bo   = (const float*)d_in[14];
    float* ws  = (float*)d_ws;
    float* out = (float*)d_out;

    hipLaunchKernelGGL(prep_kernel, dim3(64), dim3(256), 0, stream,
                       W1, Wih0, Whh0, bih0, bhh0, Wih1, Whh1, bih1, bhh1, ws);
    // 256 blocks x 4 waves x 4 batch = 4096 sequences; 1024 waves = 1 wave/SIMD
    hipLaunchKernelGGL(tft_main, dim3(256), dim3(256), 0, stream,
                       feat, W2, b1, b2, Wo, bo, ws, out);
}

// Round 2
// 2256.976 us; speedup vs baseline: 2.3014x; 2.3014x over previous
//
#include <hip/hip_runtime.h>
#include <hip/hip_fp16.h>
#include <math.h>

typedef unsigned int uint;
typedef _Float16 h2_t __attribute__((ext_vector_type(2)));

#define NT 256

// ---- LDS byte offsets (16B-aligned) ----
#define OFF_WA0 0        // uint [37][256]  L0 weights fp16 m-pairs (x~:5, h0:32)
#define OFF_WB1 37888    // uint [64][256]  L1 weights (ih1:32, hh1:32)
#define OFF_W1T 103424   // f32  [9][64]    W1 transposed
#define OFF_W2  105728   // uint [32][12]   W2 fp16 m-pairs
#define OFF_XT  107264   // f32  [16][12]   x_t per batch (8 feat + delta @8)
#define OFF_HID 108032   // uint [16][32]   VSN hidden fp16 pairs
#define OFF_XTM 110080   // uint [5][16]    x~ fp16 pairs
#define OFF_H0  110400   // uint [32][16]   h0 fp16 pairs
#define OFF_H1  112448   // uint [32][16]   h1 fp16 pairs
#define OFF_PRE 114496   // f32  [4][64][20] gate preacts (padded 20)
#define OFF_WP  134976   // f32  [16][16]   delta partials
#define LDS_BYTES 136000

// ws (float/uint words): [Wa0 | Wb1 | W1T | W2 | bs0 | bs1]
#define WSW_W1T 25856
#define WSW_W2  26432
#define WSW_BS0 26816
#define WSW_BS1 27072

__device__ __forceinline__ float fexp2(float x) { return __builtin_amdgcn_exp2f(x); }
__device__ __forceinline__ float frcp(float x)  { return __builtin_amdgcn_rcpf(x); }
__device__ __forceinline__ float sigm(float x)  { return frcp(1.0f + fexp2(-1.44269504f * x)); }
__device__ __forceinline__ float tanh_(float x) { return fmaf(2.0f, frcp(1.0f + fexp2(-2.88539008f * x)), -1.0f); }

__device__ __forceinline__ float dot2(uint w, uint x, float acc) {
#if defined(__has_builtin) && __has_builtin(__builtin_amdgcn_fdot2)
    return __builtin_amdgcn_fdot2(__builtin_bit_cast(h2_t, w), __builtin_bit_cast(h2_t, x), acc, false);
#else
    const __half2 wh = *reinterpret_cast<const __half2*>(&w);
    const __half2 xh = *reinterpret_cast<const __half2*>(&x);
    acc = fmaf(__low2float(wh), __low2float(xh), acc);
    return fmaf(__high2float(wh), __high2float(xh), acc);
#endif
}

__device__ __forceinline__ uint pack2(float lo, float hi) {
    return ((uint)__half_as_ushort(__float2half_rn(hi)) << 16) |
           (uint)__half_as_ushort(__float2half_rn(lo));
}

__global__ __launch_bounds__(1024)
void prep_kernel(const float* __restrict__ W1,  const float* __restrict__ W2,
                 const float* __restrict__ Wih0, const float* __restrict__ Whh0,
                 const float* __restrict__ bih0, const float* __restrict__ bhh0,
                 const float* __restrict__ Wih1, const float* __restrict__ Whh1,
                 const float* __restrict__ bih1, const float* __restrict__ bhh1,
                 uint* __restrict__ ws)
{
    const int tid = blockIdx.x * 1024 + threadIdx.x;
    float* wsf = (float*)ws;
    if (tid < 9472) {                       // Wa0 [37][256]
        int mp = tid >> 8, r = tid & 255;
        float lo, hi;
        if (mp < 5) { int m = 2 * mp; lo = Wih0[r * 9 + m]; hi = (m + 1 < 9) ? Wih0[r * 9 + m + 1] : 0.f; }
        else        { int m = 2 * (mp - 5); lo = Whh0[r * 64 + m]; hi = Whh0[r * 64 + m + 1]; }
        ws[tid] = pack2(lo, hi);
    }
    if (tid < 16384) {                      // Wb1 [64][256]
        int mp = tid >> 8, r = tid & 255;
        float lo, hi;
        if (mp < 32) { int m = 2 * mp; lo = Wih1[r * 64 + m]; hi = Wih1[r * 64 + m + 1]; }
        else         { int m = 2 * (mp - 32); lo = Whh1[r * 64 + m]; hi = Whh1[r * 64 + m + 1]; }
        ws[9472 + tid] = pack2(lo, hi);
    }
    if (tid < 576) {                        // W1T [9][64]
        int m = tid / 64, jj = tid % 64;
        wsf[WSW_W1T + tid] = W1[jj * 9 + m];
    }
    if (tid < 384) {                        // W2 pairs [32][12]
        int mp = tid / 12, r = tid % 12;
        ws[WSW_W2 + tid] = (r < 9) ? pack2(W2[r * 64 + 2 * mp], W2[r * 64 + 2 * mp + 1]) : 0u;
    }
    if (tid < 256) {                        // fused biases
        wsf[WSW_BS0 + tid] = bih0[tid] + bhh0[tid];
        wsf[WSW_BS1 + tid] = bih1[tid] + bhh1[tid];
    }
}

__global__ __launch_bounds__(1024)
void tft_main(const float* __restrict__ feat,
              const float* __restrict__ b1, const float* __restrict__ b2,
              const float* __restrict__ Wo, const float* __restrict__ bo,
              const uint* __restrict__ ws,
              float* __restrict__ out)
{
    extern __shared__ unsigned char smem[];
    const int tid  = threadIdx.x;
    const int lane = tid & 63;
    const int w    = tid >> 6;         // wave id = batch for VSN phases
    const int g    = w >> 2;           // gate (i,f,g,o) for matmul phases
    const int bq   = w & 3;            // batch quad for matmul phases
    const int cb   = tid & 15;         // combine: batch
    const int cj   = ((tid >> 6) << 2) | ((tid >> 4) & 3);   // combine: hidden idx
    const int b0   = blockIdx.x * 16;

    const uint*  wa0U = (const uint*)(smem + OFF_WA0);
    const uint*  wb1U = (const uint*)(smem + OFF_WB1);
    const float* w1tF = (const float*)(smem + OFF_W1T);
    const uint*  w2U  = (const uint*)(smem + OFF_W2);
    float*  xTf  = (float*)(smem + OFF_XT);
    __half* hidH = (__half*)(smem + OFF_HID);
    const uint* hidU = (const uint*)(smem + OFF_HID);
    __half* xtmH = (__half*)(smem + OFF_XTM);
    const uint* xtmU = (const uint*)(smem + OFF_XTM);
    __half* h0H  = (__half*)(smem + OFF_H0);
    const uint* h0U  = (const uint*)(smem + OFF_H0);
    __half* h1H  = (__half*)(smem + OFF_H1);
    const uint* h1U  = (const uint*)(smem + OFF_H1);
    float* preF  = (float*)(smem + OFF_PRE);
    float* wpF   = (float*)(smem + OFF_WP);

    // ---- one-time init ----
    {   // copy packed weights (107264 B) to LDS
        const float4* src = (const float4*)ws;
        float4* dst = (float4*)smem;
        #pragma unroll
        for (int i = 0; i < 7; ++i) {
            int idx = tid + i * 1024;
            if (idx < 6704) dst[idx] = src[idx];
        }
    }
    if (tid < 1024) ((uint*)(smem + OFF_H0))[tid] = 0;   // h0,h1 = 0 (contiguous)
    if (tid < 80)   ((uint*)(smem + OFF_XTM))[tid] = 0;  // x~ pads
    if (tid < 16)   xTf[tid * 12 + 8] = 0.f;

    const float* wsF  = (const float*)ws;
    const float bias0 = wsF[WSW_BS0 + (g << 6) + lane];
    const float bias1 = wsF[WSW_BS1 + (g << 6) + lane];
    const float b1v = b1[lane];
    const float b2v = b2[lane < 9 ? lane : 0];
    const float wov = Wo[cj];
    const float bov = bo[0];

    float c0 = 0.f, c1 = 0.f;
    float4 px = float4{0.f, 0.f, 0.f, 0.f};
    if (tid < 32) {   // prefetch x(t=0)
        int pb = tid >> 1, ph = tid & 1;
        px = *reinterpret_cast<const float4*>(feat + ((size_t)(b0 + pb) * NT + 0) * 8 + 4 * ph);
    }
    __syncthreads();

    for (int t = 0; t < NT; ++t) {
        // ---- TOP: finalize delta(t-1), build x_t, prefetch x(t+1) ----
        if (tid < 16) {
            float s;
            if (t > 0) {
                s = bov;
                #pragma unroll
                for (int ww = 0; ww < 16; ++ww) s += wpF[ww * 16 + tid];
                out[(size_t)(b0 + tid) * NT + (t - 1)] = s;
            } else s = 0.f;
            xTf[tid * 12 + 8] = s;
        }
        if (tid < 32) {
            int pb = tid >> 1, ph = tid & 1;
            *reinterpret_cast<float4*>(xTf + pb * 12 + 4 * ph) = px;
            if (t + 1 < NT)
                px = *reinterpret_cast<const float4*>(feat + ((size_t)(b0 + pb) * NT + t + 1) * 8 + 4 * ph);
        }
        __syncthreads();

        // ---- S1: VSN hidden = relu(x @ W1.T + b1); thread (jj=lane, b=w) ----
        {
            float acc = b1v;
            #pragma unroll
            for (int m = 0; m < 9; ++m)
                acc = fmaf(w1tF[m * 64 + lane], xTf[w * 12 + m], acc);
            acc = fmaxf(acc, 0.f);
            hidH[(w * 32 + (lane >> 1)) * 2 + (lane & 1)] = __float2half_rn(acc);
        }
        __syncthreads();

        // ---- S2: logits + softmax + x~ ; wave w = batch, lanes 0..8 = r ----
        if (lane < 9) {
            float acc = b2v;
            #pragma unroll 8
            for (int mp = 0; mp < 32; ++mp)
                acc = dot2(w2U[mp * 12 + lane], hidU[w * 32 + mp], acc);
            preF[w * 20 + lane] = acc;       // scratch (pre is free here)
            float mx = acc;
            float lg[9];
            #pragma unroll
            for (int r = 0; r < 9; ++r) { lg[r] = preF[w * 20 + r]; mx = fmaxf(mx, lg[r]); }
            float sum = 0.f;
            #pragma unroll
            for (int r = 0; r < 9; ++r) sum += fexp2(1.44269504f * (lg[r] - mx));
            float eo = fexp2(1.44269504f * (acc - mx));
            float xsel = xTf[w * 12 + lane] * eo * frcp(sum);
            xtmH[((lane >> 1) * 16 + w) * 2 + (lane & 1)] = __float2half_rn(xsel);
        }
        __syncthreads();

        // ---- S3: LSTM-0 preacts; wave (g,bq), lane = j ----
        {
            float a0 = bias0, a1 = bias0, a2 = bias0, a3 = bias0;
            const uint* wa = wa0U + (g << 6) + lane;
            #pragma unroll
            for (int mp = 0; mp < 5; ++mp) {
                uint wv = wa[mp * 256];
                uint4 x4 = *reinterpret_cast<const uint4*>(xtmU + mp * 16 + 4 * bq);
                a0 = dot2(wv, x4.x, a0); a1 = dot2(wv, x4.y, a1);
                a2 = dot2(wv, x4.z, a2); a3 = dot2(wv, x4.w, a3);
            }
            #pragma unroll 8
            for (int mp = 0; mp < 32; ++mp) {
                uint wv = wa[(5 + mp) * 256];
                uint4 h4 = *reinterpret_cast<const uint4*>(h0U + mp * 16 + 4 * bq);
                a0 = dot2(wv, h4.x, a0); a1 = dot2(wv, h4.y, a1);
                a2 = dot2(wv, h4.z, a2); a3 = dot2(wv, h4.w, a3);
            }
            *reinterpret_cast<float4*>(preF + g * 1280 + lane * 20 + 4 * bq) = float4{a0, a1, a2, a3};
        }
        __syncthreads();

        // ---- S4: combine gates L0; thread (cj, cb); c0 in regs ----
        {
            const int base = cj * 20 + cb;
            float ii = sigm(preF[base]);
            float ff = sigm(preF[1280 + base]);
            float gg = tanh_(preF[2560 + base]);
            float oo = sigm(preF[3840 + base]);
            c0 = ff * c0 + ii * gg;
            float hh = oo * tanh_(c0);
            h0H[((cj >> 1) * 16 + cb) * 2 + (cj & 1)] = __float2half_rn(hh);
        }
        __syncthreads();

        // ---- S5: LSTM-1 preacts ----
        {
            float a0 = bias1, a1 = bias1, a2 = bias1, a3 = bias1;
            const uint* wb = wb1U + (g << 6) + lane;
            #pragma unroll 8
            for (int mp = 0; mp < 32; ++mp) {
                uint wv = wb[mp * 256];
                uint4 h4 = *reinterpret_cast<const uint4*>(h0U + mp * 16 + 4 * bq);
                a0 = dot2(wv, h4.x, a0); a1 = dot2(wv, h4.y, a1);
                a2 = dot2(wv, h4.z, a2); a3 = dot2(wv, h4.w, a3);
            }
            #pragma unroll 8
            for (int mp = 0; mp < 32; ++mp) {
                uint wv = wb[(32 + mp) * 256];
                uint4 h4 = *reinterpret_cast<const uint4*>(h1U + mp * 16 + 4 * bq);
                a0 = dot2(wv, h4.x, a0); a1 = dot2(wv, h4.y, a1);
                a2 = dot2(wv, h4.z, a2); a3 = dot2(wv, h4.w, a3);
            }
            *reinterpret_cast<float4*>(preF + g * 1280 + lane * 20 + 4 * bq) = float4{a0, a1, a2, a3};
        }
        __syncthreads();

        // ---- S6: combine gates L1 + delta partials ----
        {
            const int base = cj * 20 + cb;
            float ii = sigm(preF[base]);
            float ff = sigm(preF[1280 + base]);
            float gg = tanh_(preF[2560 + base]);
            float oo = sigm(preF[3840 + base]);
            c1 = ff * c1 + ii * gg;
            float hh = oo * tanh_(c1);
            h1H[((cj >> 1) * 16 + cb) * 2 + (cj & 1)] = __float2half_rn(hh);
            float p = wov * hh;
            p += __shfl_xor(p, 16, 64);
            p += __shfl_xor(p, 32, 64);
            if (((tid >> 4) & 3) == 0) wpF[(tid >> 6) * 16 + cb] = p;
        }
        __syncthreads();
    }

    // ---- epilogue: delta for t = 255 ----
    if (tid < 16) {
        float s = bov;
        #pragma unroll
        for (int ww = 0; ww < 16; ++ww) s += wpF[ww * 16 + tid];
        out[(size_t)(b0 + tid) * NT + (NT - 1)] = s;
    }
}

extern "C" void kernel_launch(void* const* d_in, const int* in_sizes, int n_in,
                              void* d_out, int out_size, void* d_ws, size_t ws_size,
                              hipStream_t stream) {
    const float* feat = (const float*)d_in[0];
    const float* W1   = (const float*)d_in[1];
    const float* b1   = (const float*)d_in[2];
    const float* W2   = (const float*)d_in[3];
    const float* b2   = (const float*)d_in[4];
    const float* Wih0 = (const float*)d_in[5];
    const float* Whh0 = (const float*)d_in[6];
    const float* bih0 = (const float*)d_in[7];
    const float* bhh0 = (const float*)d_in[8];
    const float* Wih1 = (const float*)d_in[9];
    const float* Whh1 = (const float*)d_in[10];
    const float* bih1 = (const float*)d_in[11];
    const float* bhh1 = (const float*)d_in[12];
    const float* Wo   = (const float*)d_in[13];
    const float* bo   = (const float*)d_in[14];
    uint* ws   = (uint*)d_ws;
    float* out = (float*)d_out;

    hipFuncSetAttribute(reinterpret_cast<const void*>(tft_main),
                        hipFuncAttributeMaxDynamicSharedMemorySize, LDS_BYTES);

    hipLaunchKernelGGL(prep_kernel, dim3(16), dim3(1024), 0, stream,
                       W1, W2, Wih0, Whh0, bih0, bhh0, Wih1, Whh1, bih1, bhh1, ws);
    // 256 blocks x 1024 threads: one persistent block per CU, 16 batches each
    hipLaunchKernelGGL(tft_main, dim3(256), dim3(1024), LDS_BYTES, stream,
                       feat, b1, b2, Wo, bo, ws, out);
}

// Round 3
// 469.777 us; speedup vs baseline: 11.0568x; 4.8044x over previous
//
#include <hip/hip_runtime.h>
#include <hip/hip_fp16.h>
#include <math.h>

typedef unsigned int uint;
typedef _Float16 f16x8 __attribute__((ext_vector_type(8)));
typedef float f32x4 __attribute__((ext_vector_type(4)));

#define NT 256

// ---------------- ws layout (uint/f32 words) ----------------
// 0     : W_l0 frags   [16 tiles][3 ksteps][64 lanes][4 uint]  = 12288
// 12288 : W_l1 frags   [16][4][64][4]                          = 16384
// 28672 : W_v1 frags   [4][64][4]                              = 1024
// 29696 : W_v2 frags   [2][64][4]                              = 512
// 30208 : b1frag  f32  [4][64][4]                              = 1024
// 31232 : b2frag  f32  [64][4]                                 = 256
// 31488 : bias0frag f32 [16][64][4]                            = 4096
// 35584 : bias1frag f32 [16][64][4]                            = 4096
// total 39680 words = 158720 B

// ---------------- LDS byte offsets ----------------
#define O_WL0  0        // 49152
#define O_WL1  49152    // 65536
#define O_WV1  114688   // 4096
#define O_WV2  118784   // 2048
#define O_XF   120832   // f32 [16][16]   x_t raw (k0..7 feat, k8 delta, rest 0)
#define O_XB   121856   // f16 [16][80B]  x_t raw f16 (k 0..31, pad rows)
#define O_HID  123136   // f16 [16][144B] VSN hidden (k 0..63)
#define O_XS   125440   // f16 [16][80B]  x~ selected
#define O_BUF0 126720   // f16 [16][272B] h0 (k0..63) | h1 (k64..127)
#define O_BUF1 131072
#define O_WP   135424   // f32 [16 b][16 w] delta partials
#define LDS_BYTES 136448

__device__ __forceinline__ float fexp2(float x) { return __builtin_amdgcn_exp2f(x); }
__device__ __forceinline__ float frcp(float x)  { return __builtin_amdgcn_rcpf(x); }
__device__ __forceinline__ float sigm(float x)  { return frcp(1.0f + fexp2(-1.44269504f * x)); }
__device__ __forceinline__ float tanh_(float x) { return fmaf(2.0f, frcp(1.0f + fexp2(-2.88539008f * x)), -1.0f); }

__device__ __forceinline__ uint pack2(float lo, float hi) {
    return ((uint)__half_as_ushort(__float2half_rn(hi)) << 16) |
           (uint)__half_as_ushort(__float2half_rn(lo));
}
__device__ __forceinline__ unsigned short f16b(float x) {
    return __half_as_ushort(__float2half_rn(x));
}

// Pack weights into exact MFMA A-fragment order.
// A-frag (16x16x32 f16): lane l holds A[row16 = l&15][k = (l>>4)*8 + e], e=0..7.
// LSTM tiles use gate-interleaved rows: row16 = 4q + r  ->  R = r*64 + 4w + q.
__global__ __launch_bounds__(1024)
void prep_kernel(const float* __restrict__ W1,  const float* __restrict__ b1,
                 const float* __restrict__ W2,  const float* __restrict__ b2,
                 const float* __restrict__ Wih0, const float* __restrict__ Whh0,
                 const float* __restrict__ bih0, const float* __restrict__ bhh0,
                 const float* __restrict__ Wih1, const float* __restrict__ Whh1,
                 const float* __restrict__ bih1, const float* __restrict__ bhh1,
                 uint* __restrict__ ws)
{
    const int tid = blockIdx.x * 1024 + threadIdx.x;
    float* wsf = (float*)ws;

    if (tid < 12288) {                               // W_l0
        int v = tid & 3, l = (tid >> 2) & 63, ts = tid >> 8;
        int s = ts % 3, w = ts / 3;
        int R = (l & 3) * 64 + 4 * w + ((l >> 2) & 3);
        int k0 = (l >> 4) * 8 + 2 * v;
        float lo, hi;
        if (s == 0) {
            lo = (k0     < 9) ? Wih0[R * 9 + k0]     : 0.f;
            hi = (k0 + 1 < 9) ? Wih0[R * 9 + k0 + 1] : 0.f;
        } else {
            int kh = 32 * (s - 1) + k0;
            lo = Whh0[R * 64 + kh]; hi = Whh0[R * 64 + kh + 1];
        }
        ws[tid] = pack2(lo, hi);
    } else if (tid < 28672) {                        // W_l1
        int idx = tid - 12288;
        int v = idx & 3, l = (idx >> 2) & 63, ts = idx >> 8;
        int s = ts & 3, w = ts >> 2;
        int R = (l & 3) * 64 + 4 * w + ((l >> 2) & 3);
        int kt = 32 * s + (l >> 4) * 8 + 2 * v;
        float lo, hi;
        if (kt < 64) { lo = Wih1[R * 64 + kt];      hi = Wih1[R * 64 + kt + 1]; }
        else         { lo = Whh1[R * 64 + kt - 64]; hi = Whh1[R * 64 + kt - 63]; }
        ws[tid] = pack2(lo, hi);
    } else if (tid < 29696) {                        // W_v1 (no row remap)
        int idx = tid - 28672;
        int v = idx & 3, l = (idx >> 2) & 63, m = idx >> 8;
        int j2 = 16 * m + (l & 15);
        int k0 = (l >> 4) * 8 + 2 * v;
        float lo = (k0     < 9) ? W1[j2 * 9 + k0]     : 0.f;
        float hi = (k0 + 1 < 9) ? W1[j2 * 9 + k0 + 1] : 0.f;
        ws[tid] = pack2(lo, hi);
    } else if (tid < 30208) {                        // W_v2 (rows padded to 16)
        int idx = tid - 29696;
        int v = idx & 3, l = (idx >> 2) & 63, s = idx >> 8;
        int rr = l & 15;
        int k0 = 32 * s + (l >> 4) * 8 + 2 * v;
        float lo = (rr < 9) ? W2[rr * 64 + k0]     : 0.f;
        float hi = (rr < 9) ? W2[rr * 64 + k0 + 1] : 0.f;
        ws[tid] = pack2(lo, hi);
    } else if (tid < 31232) {                        // b1frag
        int idx = tid - 30208;
        int r = idx & 3, l = (idx >> 2) & 63, m = idx >> 8;
        wsf[tid] = b1[16 * m + (l >> 4) * 4 + r];
    } else if (tid < 31488) {                        // b2frag (-1e30 pad rows)
        int idx = tid - 31232;
        int r = idx & 3, l = idx >> 2;
        int row = (l >> 4) * 4 + r;
        wsf[tid] = (row < 9) ? b2[row] : -1e30f;
    } else if (tid < 35584) {                        // bias0frag
        int idx = tid - 31488;
        int r = idx & 3, l = (idx >> 2) & 63, w = idx >> 8;
        int R = r * 64 + 4 * w + (l >> 4);
        wsf[tid] = bih0[R] + bhh0[R];
    } else if (tid < 39680) {                        // bias1frag
        int idx = tid - 35584;
        int r = idx & 3, l = (idx >> 2) & 63, w = idx >> 8;
        int R = r * 64 + 4 * w + (l >> 4);
        wsf[tid] = bih1[R] + bhh1[R];
    }
}

__global__ __launch_bounds__(1024)
void tft_main(const float* __restrict__ feat,
              const float* __restrict__ Wo, const float* __restrict__ bo,
              const uint* __restrict__ ws,
              float* __restrict__ out)
{
    extern __shared__ unsigned char smem[];
    const int tid  = threadIdx.x;
    const int lane = tid & 63;
    const int w    = tid >> 6;        // wave id = M-tile
    const int q    = lane >> 4;       // k-group / C row-group
    const int cb   = lane & 15;       // batch column
    const int b0   = blockIdx.x * 16;

    // ---- one-time: copy packed weights to LDS, zero dynamic area ----
    {
        const uint4* src = (const uint4*)ws;
        uint4* dst = (uint4*)smem;
        #pragma unroll
        for (int i = 0; i < 8; ++i) {
            int idx = tid + i * 1024;
            if (idx < 7552) dst[idx] = src[idx];
        }
        uint4 z = {0u, 0u, 0u, 0u};
        if (tid < 976) ((uint4*)(smem + O_XF))[tid] = z;
    }

    const float* wsf = (const float*)ws;
    const float4 bias0 = *(const float4*)(wsf + 31488 + (w * 64 + lane) * 4);
    const float4 bias1 = *(const float4*)(wsf + 35584 + (w * 64 + lane) * 4);
    float4 b1f = {0.f, 0.f, 0.f, 0.f};
    float4 b2f = {0.f, 0.f, 0.f, 0.f};
    if (w < 4)  b1f = *(const float4*)(wsf + 30208 + (w * 64 + lane) * 4);
    if (w == 4) b2f = *(const float4*)(wsf + 31232 + lane * 4);
    const float woj = Wo[4 * w + q];
    const float bov = bo[0];

    float c0 = 0.f, c1 = 0.f;
    float4 px = {0.f, 0.f, 0.f, 0.f};
    if (tid < 32) {
        int pb = tid >> 1, ph = tid & 1;
        px = *(const float4*)(feat + ((size_t)(b0 + pb) * NT) * 8 + 4 * ph);
    }
    __syncthreads();

    // hoisted pointers
    const unsigned char* pWL0 = smem + O_WL0 + w * 3072 + lane * 16;
    const unsigned char* pWL1 = smem + O_WL1 + w * 4096 + lane * 16;

    for (int t = 0; t < NT; ++t) {
        const int cur = t & 1;
        unsigned char* bufC = smem + (cur ? O_BUF1 : O_BUF0);
        unsigned char* bufP = smem + (cur ? O_BUF0 : O_BUF1);

        // ---- TOP: finalize delta(t-1), stage x_t, prefetch x(t+1) ----
        if (tid < 16) {
            float s = bov;
            if (t > 0) {
                const float* wp = (const float*)(smem + O_WP) + tid * 16;
                float4 s0 = *(const float4*)(wp);
                float4 s1 = *(const float4*)(wp + 4);
                float4 s2 = *(const float4*)(wp + 8);
                float4 s3 = *(const float4*)(wp + 12);
                s += s0.x + s0.y + s0.z + s0.w + s1.x + s1.y + s1.z + s1.w
                   + s2.x + s2.y + s2.z + s2.w + s3.x + s3.y + s3.z + s3.w;
                out[(size_t)(b0 + tid) * NT + (t - 1)] = s;
            } else s = 0.f;
            ((float*)(smem + O_XF))[tid * 16 + 8] = s;
            *(unsigned short*)(smem + O_XB + tid * 80 + 16) = f16b(s);
        }
        if (tid < 32) {
            int pb = tid >> 1, ph = tid & 1;
            *(float4*)((float*)(smem + O_XF) + pb * 16 + 4 * ph) = px;
            uint2 p2; p2.x = pack2(px.x, px.y); p2.y = pack2(px.z, px.w);
            *(uint2*)(smem + O_XB + pb * 80 + ph * 8) = p2;
            if (t + 1 < NT)
                px = *(const float4*)(feat + ((size_t)(b0 + pb) * NT + (t + 1)) * 8 + 4 * ph);
        }
        __syncthreads();   // A

        // ---- VSN1: hid = relu(W1 x + b1); waves 0..3 ----
        if (w < 4) {
            f16x8 a = *(const f16x8*)(smem + O_WV1 + (w * 64 + lane) * 16);
            f16x8 b = *(const f16x8*)(smem + O_XB + cb * 80 + q * 16);
            f32x4 acc = {b1f.x, b1f.y, b1f.z, b1f.w};
            acc = __builtin_amdgcn_mfma_f32_16x16x32_f16(a, b, acc, 0, 0, 0);
            int j2b = 16 * w + 4 * q;     // rows j2b..j2b+3
            *(uint*)(smem + O_HID + cb * 144 + j2b * 2)     = pack2(fmaxf(acc[0], 0.f), fmaxf(acc[1], 0.f));
            *(uint*)(smem + O_HID + cb * 144 + j2b * 2 + 4) = pack2(fmaxf(acc[2], 0.f), fmaxf(acc[3], 0.f));
        }
        __syncthreads();   // B

        // ---- VSN2 + softmax + x~ ; wave 4 only, fully in-register ----
        if (w == 4) {
            f32x4 acc = {b2f.x, b2f.y, b2f.z, b2f.w};
            f16x8 a0 = *(const f16x8*)(smem + O_WV2 + lane * 16);
            f16x8 a1 = *(const f16x8*)(smem + O_WV2 + 1024 + lane * 16);
            f16x8 h0 = *(const f16x8*)(smem + O_HID + cb * 144 + q * 16);
            f16x8 h1 = *(const f16x8*)(smem + O_HID + cb * 144 + 64 + q * 16);
            acc = __builtin_amdgcn_mfma_f32_16x16x32_f16(a0, h0, acc, 0, 0, 0);
            acc = __builtin_amdgcn_mfma_f32_16x16x32_f16(a1, h1, acc, 0, 0, 0);
            float mx = fmaxf(fmaxf(acc[0], acc[1]), fmaxf(acc[2], acc[3]));
            mx = fmaxf(mx, __shfl_xor(mx, 16, 64));
            mx = fmaxf(mx, __shfl_xor(mx, 32, 64));
            float e0 = fexp2(1.44269504f * (acc[0] - mx));
            float e1 = fexp2(1.44269504f * (acc[1] - mx));
            float e2 = fexp2(1.44269504f * (acc[2] - mx));
            float e3 = fexp2(1.44269504f * (acc[3] - mx));
            float sm = e0 + e1 + e2 + e3;
            sm += __shfl_xor(sm, 16, 64);
            sm += __shfl_xor(sm, 32, 64);
            float inv = frcp(sm);
            const float* xf = (const float*)(smem + O_XF) + cb * 16 + 4 * q;
            float v0 = xf[0] * e0 * inv;
            float v1 = xf[1] * e1 * inv;
            float v2 = xf[2] * e2 * inv;
            float v3 = xf[3] * e3 * inv;
            *(uint*)(smem + O_XS + cb * 80 + 8 * q)     = pack2(v0, v1);
            *(uint*)(smem + O_XS + cb * 80 + 8 * q + 4) = pack2(v2, v3);
        }
        __syncthreads();   // C

        // ---- LSTM0: 3 MFMA + in-register gates; lane owns (j = 4w+q, b=cb) ----
        float h0v;
        {
            f16x8 a0 = *(const f16x8*)(pWL0);
            f16x8 a1 = *(const f16x8*)(pWL0 + 1024);
            f16x8 a2 = *(const f16x8*)(pWL0 + 2048);
            f16x8 bb0 = *(const f16x8*)(smem + O_XS + cb * 80 + q * 16);
            f16x8 bb1 = *(const f16x8*)(bufP + cb * 272 + q * 16);
            f16x8 bb2 = *(const f16x8*)(bufP + cb * 272 + 64 + q * 16);
            f32x4 acc = {bias0.x, bias0.y, bias0.z, bias0.w};
            acc = __builtin_amdgcn_mfma_f32_16x16x32_f16(a0, bb0, acc, 0, 0, 0);
            acc = __builtin_amdgcn_mfma_f32_16x16x32_f16(a1, bb1, acc, 0, 0, 0);
            acc = __builtin_amdgcn_mfma_f32_16x16x32_f16(a2, bb2, acc, 0, 0, 0);
            float ii = sigm(acc[0]), ff = sigm(acc[1]);
            float gg = tanh_(acc[2]), oo = sigm(acc[3]);
            c0 = ff * c0 + ii * gg;
            h0v = oo * tanh_(c0);
            int j = 4 * w + q;
            *(unsigned short*)(bufC + cb * 272 + j * 2) = f16b(h0v);
        }
        __syncthreads();   // D

        // ---- LSTM1: 4 MFMA + in-register gates + delta partial ----
        {
            f16x8 a0 = *(const f16x8*)(pWL1);
            f16x8 a1 = *(const f16x8*)(pWL1 + 1024);
            f16x8 a2 = *(const f16x8*)(pWL1 + 2048);
            f16x8 a3 = *(const f16x8*)(pWL1 + 3072);
            f16x8 bb0 = *(const f16x8*)(bufC + cb * 272 + q * 16);        // h0 new
            f16x8 bb1 = *(const f16x8*)(bufC + cb * 272 + 64 + q * 16);
            f16x8 bb2 = *(const f16x8*)(bufP + cb * 272 + 128 + q * 16);  // h1 old
            f16x8 bb3 = *(const f16x8*)(bufP + cb * 272 + 192 + q * 16);
            f32x4 acc = {bias1.x, bias1.y, bias1.z, bias1.w};
            acc = __builtin_amdgcn_mfma_f32_16x16x32_f16(a0, bb0, acc, 0, 0, 0);
            acc = __builtin_amdgcn_mfma_f32_16x16x32_f16(a1, bb1, acc, 0, 0, 0);
            acc = __builtin_amdgcn_mfma_f32_16x16x32_f16(a2, bb2, acc, 0, 0, 0);
            acc = __builtin_amdgcn_mfma_f32_16x16x32_f16(a3, bb3, acc, 0, 0, 0);
            float ii = sigm(acc[0]), ff = sigm(acc[1]);
            float gg = tanh_(acc[2]), oo = sigm(acc[3]);
            c1 = ff * c1 + ii * gg;
            float h1v = oo * tanh_(c1);
            int j = 4 * w + q;
            *(unsigned short*)(bufC + cb * 272 + 128 + j * 2) = f16b(h1v);
            float p = woj * h1v;
            p += __shfl_xor(p, 16, 64);
            p += __shfl_xor(p, 32, 64);
            if (q == 0) ((float*)(smem + O_WP))[cb * 16 + w] = p;
        }
        __syncthreads();   // E
    }

    // ---- epilogue: delta for t = 255 ----
    if (tid < 16) {
        const float* wp = (const float*)(smem + O_WP) + tid * 16;
        float4 s0 = *(const float4*)(wp);
        float4 s1 = *(const float4*)(wp + 4);
        float4 s2 = *(const float4*)(wp + 8);
        float4 s3 = *(const float4*)(wp + 12);
        float s = bov + s0.x + s0.y + s0.z + s0.w + s1.x + s1.y + s1.z + s1.w
                + s2.x + s2.y + s2.z + s2.w + s3.x + s3.y + s3.z + s3.w;
        out[(size_t)(b0 + tid) * NT + (NT - 1)] = s;
    }
}

extern "C" void kernel_launch(void* const* d_in, const int* in_sizes, int n_in,
                              void* d_out, int out_size, void* d_ws, size_t ws_size,
                              hipStream_t stream) {
    const float* feat = (const float*)d_in[0];
    const float* W1   = (const float*)d_in[1];
    const float* b1   = (const float*)d_in[2];
    const float* W2   = (const float*)d_in[3];
    const float* b2   = (const float*)d_in[4];
    const float* Wih0 = (const float*)d_in[5];
    const float* Whh0 = (const float*)d_in[6];
    const float* bih0 = (const float*)d_in[7];
    const float* bhh0 = (const float*)d_in[8];
    const float* Wih1 = (const float*)d_in[9];
    const float* Whh1 = (const float*)d_in[10];
    const float* bih1 = (const float*)d_in[11];
    const float* bhh1 = (const float*)d_in[12];
    const float* Wo   = (const float*)d_in[13];
    const float* bo   = (const float*)d_in[14];
    uint* ws   = (uint*)d_ws;
    float* out = (float*)d_out;

    hipFuncSetAttribute(reinterpret_cast<const void*>(tft_main),
                        hipFuncAttributeMaxDynamicSharedMemorySize, LDS_BYTES);

    hipLaunchKernelGGL(prep_kernel, dim3(40), dim3(1024), 0, stream,
                       W1, b1, W2, b2, Wih0, Whh0, bih0, bhh0,
                       Wih1, Whh1, bih1, bhh1, ws);
    hipLaunchKernelGGL(tft_main, dim3(256), dim3(1024), LDS_BYTES, stream,
                       feat, Wo, bo, ws, out);
}

// Round 4
// 410.853 us; speedup vs baseline: 12.6426x; 1.1434x over previous
//
#include <hip/hip_runtime.h>
#include <hip/hip_fp16.h>
#include <math.h>

typedef unsigned int uint;
typedef _Float16 f16x8 __attribute__((ext_vector_type(8)));
typedef float f32x4 __attribute__((ext_vector_type(4)));

#define NT 256

// ---------------- ws layout (uint/f32 words) ----------------
// 0     : W_l0 frags   [16 tiles][3 ksteps][64 lanes][4 uint]  = 12288
// 12288 : W_l1 frags   [16][4][64][4]                          = 16384
// 28672 : W_v1 frags   [4][64][4]                              = 1024
// 29696 : W_v2 frags   [2][64][4]                              = 512
// 30208 : b1frag  f32  [4][64][4]                              = 1024
// 31232 : b2frag  f32  [64][4]                                 = 256
// 31488 : bias0frag f32 [16][64][4]                            = 4096
// 35584 : bias1frag f32 [16][64][4]                            = 4096
// total 39680 words

// ---------------- LDS byte offsets (all 16B-aligned) ----------------
#define O_XF   0        // f32 [16][16]   x_t raw (k0..7 feat, k8 delta, rest 0)
#define O_XB   1024     // f16 [16][80B]  x_t f16 (k0..8, rest 0)
#define O_HID  2304     // f16 [16][144B] VSN hidden (k0..63)
#define O_XS   4608     // f16 [16][80B]  x~ selected (k0..15 written, 16..31 zero)
#define O_BUF0 5888     // f16 [16][272B] h0 (k0..63) | h1 (k64..127)
#define O_BUF1 10240
#define O_WP   14592    // f32 [16 b][20]  delta partials (stride 20 floats)
#define LDS_BYTES 15872

__device__ __forceinline__ float fexp2(float x) { return __builtin_amdgcn_exp2f(x); }
__device__ __forceinline__ float frcp(float x)  { return __builtin_amdgcn_rcpf(x); }
__device__ __forceinline__ float sigm(float x)  { return frcp(1.0f + fexp2(-1.44269504f * x)); }
__device__ __forceinline__ float tanh_(float x) { return fmaf(2.0f, frcp(1.0f + fexp2(-2.88539008f * x)), -1.0f); }

__device__ __forceinline__ uint pack2(float lo, float hi) {
    return ((uint)__half_as_ushort(__float2half_rn(hi)) << 16) |
           (uint)__half_as_ushort(__float2half_rn(lo));
}
__device__ __forceinline__ unsigned short f16b(float x) {
    return __half_as_ushort(__float2half_rn(x));
}
__device__ __forceinline__ f16x8 ldfrag(const uint* p) {
    union { uint4 u; f16x8 h; } c;
    c.u = *(const uint4*)p;
    return c.h;
}

// Pack weights into exact MFMA A-fragment order.
// A-frag (16x16x32 f16): lane l holds A[row16 = l&15][k = (l>>4)*8 + e], e=0..7.
// LSTM tiles use gate-interleaved rows: row16 = 4q + r  ->  R = r*64 + 4w + q.
__global__ __launch_bounds__(1024)
void prep_kernel(const float* __restrict__ W1,  const float* __restrict__ b1,
                 const float* __restrict__ W2,  const float* __restrict__ b2,
                 const float* __restrict__ Wih0, const float* __restrict__ Whh0,
                 const float* __restrict__ bih0, const float* __restrict__ bhh0,
                 const float* __restrict__ Wih1, const float* __restrict__ Whh1,
                 const float* __restrict__ bih1, const float* __restrict__ bhh1,
                 uint* __restrict__ ws)
{
    const int tid = blockIdx.x * 1024 + threadIdx.x;
    float* wsf = (float*)ws;

    if (tid < 12288) {                               // W_l0
        int v = tid & 3, l = (tid >> 2) & 63, ts = tid >> 8;
        int s = ts % 3, w = ts / 3;
        int R = (l & 3) * 64 + 4 * w + ((l >> 2) & 3);
        int k0 = (l >> 4) * 8 + 2 * v;
        float lo, hi;
        if (s == 0) {
            lo = (k0     < 9) ? Wih0[R * 9 + k0]     : 0.f;
            hi = (k0 + 1 < 9) ? Wih0[R * 9 + k0 + 1] : 0.f;
        } else {
            int kh = 32 * (s - 1) + k0;
            lo = Whh0[R * 64 + kh]; hi = Whh0[R * 64 + kh + 1];
        }
        ws[tid] = pack2(lo, hi);
    } else if (tid < 28672) {                        // W_l1
        int idx = tid - 12288;
        int v = idx & 3, l = (idx >> 2) & 63, ts = idx >> 8;
        int s = ts & 3, w = ts >> 2;
        int R = (l & 3) * 64 + 4 * w + ((l >> 2) & 3);
        int kt = 32 * s + (l >> 4) * 8 + 2 * v;
        float lo, hi;
        if (kt < 64) { lo = Wih1[R * 64 + kt];      hi = Wih1[R * 64 + kt + 1]; }
        else         { lo = Whh1[R * 64 + kt - 64]; hi = Whh1[R * 64 + kt - 63]; }
        ws[tid] = pack2(lo, hi);
    } else if (tid < 29696) {                        // W_v1 (no row remap)
        int idx = tid - 28672;
        int v = idx & 3, l = (idx >> 2) & 63, m = idx >> 8;
        int j2 = 16 * m + (l & 15);
        int k0 = (l >> 4) * 8 + 2 * v;
        float lo = (k0     < 9) ? W1[j2 * 9 + k0]     : 0.f;
        float hi = (k0 + 1 < 9) ? W1[j2 * 9 + k0 + 1] : 0.f;
        ws[tid] = pack2(lo, hi);
    } else if (tid < 30208) {                        // W_v2 (rows padded to 16)
        int idx = tid - 29696;
        int v = idx & 3, l = (idx >> 2) & 63, s = idx >> 8;
        int rr = l & 15;
        int k0 = 32 * s + (l >> 4) * 8 + 2 * v;
        float lo = (rr < 9) ? W2[rr * 64 + k0]     : 0.f;
        float hi = (rr < 9) ? W2[rr * 64 + k0 + 1] : 0.f;
        ws[tid] = pack2(lo, hi);
    } else if (tid < 31232) {                        // b1frag
        int idx = tid - 30208;
        int r = idx & 3, l = (idx >> 2) & 63, m = idx >> 8;
        wsf[tid] = b1[16 * m + (l >> 4) * 4 + r];
    } else if (tid < 31488) {                        // b2frag (-1e30 pad rows)
        int idx = tid - 31232;
        int r = idx & 3, l = idx >> 2;
        int row = (l >> 4) * 4 + r;
        wsf[tid] = (row < 9) ? b2[row] : -1e30f;
    } else if (tid < 35584) {                        // bias0frag
        int idx = tid - 31488;
        int r = idx & 3, l = (idx >> 2) & 63, w = idx >> 8;
        int R = r * 64 + 4 * w + (l >> 4);
        wsf[tid] = bih0[R] + bhh0[R];
    } else if (tid < 39680) {                        // bias1frag
        int idx = tid - 35584;
        int r = idx & 3, l = (idx >> 2) & 63, w = idx >> 8;
        int R = r * 64 + 4 * w + (l >> 4);
        wsf[tid] = bih1[R] + bhh1[R];
    }
}

__global__ __launch_bounds__(1024)
void tft_main(const float* __restrict__ feat,
              const float* __restrict__ Wo, const float* __restrict__ bo,
              const uint* __restrict__ ws,
              float* __restrict__ out)
{
    __shared__ unsigned char smem[LDS_BYTES];
    const int tid  = threadIdx.x;
    const int lane = tid & 63;
    const int w    = tid >> 6;        // wave id = M-tile
    const int q    = lane >> 4;       // k-group / C row-group
    const int cb   = lane & 15;       // batch column
    const int b0   = blockIdx.x * 16;

    // zero all dynamic LDS once
    {
        uint4 z = {0u, 0u, 0u, 0u};
        if (tid < LDS_BYTES / 16) ((uint4*)smem)[tid] = z;
    }

    // ---- weights -> registers (once) ----
    const f16x8 wl0_0 = ldfrag(ws + (w * 3 + 0) * 256 + lane * 4);   // Wih0 (x~, K0..31)
    const f16x8 wl0_1 = ldfrag(ws + (w * 3 + 1) * 256 + lane * 4);   // Whh0 K0..31
    const f16x8 wl0_2 = ldfrag(ws + (w * 3 + 2) * 256 + lane * 4);   // Whh0 K32..63
    const f16x8 wl1_0 = ldfrag(ws + 12288 + (w * 4 + 0) * 256 + lane * 4); // Wih1 K0..31
    const f16x8 wl1_1 = ldfrag(ws + 12288 + (w * 4 + 1) * 256 + lane * 4); // Wih1 K32..63
    const f16x8 wl1_2 = ldfrag(ws + 12288 + (w * 4 + 2) * 256 + lane * 4); // Whh1 K0..31
    const f16x8 wl1_3 = ldfrag(ws + 12288 + (w * 4 + 3) * 256 + lane * 4); // Whh1 K32..63
    f16x8 wv1 = {}, wv2_0 = {}, wv2_1 = {};
    if (w < 4)  wv1   = ldfrag(ws + 28672 + w * 256 + lane * 4);
    if (w == 4) {
        wv2_0 = ldfrag(ws + 29696 + lane * 4);
        wv2_1 = ldfrag(ws + 29696 + 256 + lane * 4);
    }
    const float* wsf = (const float*)ws;
    const float4 bias0 = *(const float4*)(wsf + 31488 + (w * 64 + lane) * 4);
    const float4 bias1 = *(const float4*)(wsf + 35584 + (w * 64 + lane) * 4);
    float4 b1f = {0.f, 0.f, 0.f, 0.f};
    float4 b2f = {0.f, 0.f, 0.f, 0.f};
    if (w < 4)  b1f = *(const float4*)(wsf + 30208 + (w * 64 + lane) * 4);
    if (w == 4) b2f = *(const float4*)(wsf + 31232 + lane * 4);
    const float woj = Wo[4 * w + q];
    const float bov = bo[0];

    float c0 = 0.f, c1 = 0.f;
    float4 px = {0.f, 0.f, 0.f, 0.f};
    if (tid < 32) {
        int pb = tid >> 1, ph = tid & 1;
        px = *(const float4*)(feat + ((size_t)(b0 + pb) * NT) * 8 + 4 * ph);
    }
    __syncthreads();

    for (int t = 0; t < NT; ++t) {
        unsigned char* bufC = smem + ((t & 1) ? O_BUF1 : O_BUF0);
        unsigned char* bufP = smem + ((t & 1) ? O_BUF0 : O_BUF1);

        // ---- P0: delta finalize + x stage + look-ahead recurrent MFMAs ----
        if (tid < 16) {
            float s = bov;
            if (t > 0) {
                const float* wp = (const float*)(smem + O_WP) + tid * 20;
                float4 s0 = *(const float4*)(wp);
                float4 s1 = *(const float4*)(wp + 4);
                float4 s2 = *(const float4*)(wp + 8);
                float4 s3 = *(const float4*)(wp + 12);
                s += s0.x + s0.y + s0.z + s0.w + s1.x + s1.y + s1.z + s1.w
                   + s2.x + s2.y + s2.z + s2.w + s3.x + s3.y + s3.z + s3.w;
                out[(size_t)(b0 + tid) * NT + (t - 1)] = s;
            } else s = 0.f;
            ((float*)(smem + O_XF))[tid * 16 + 8] = s;
            *(unsigned short*)(smem + O_XB + tid * 80 + 16) = f16b(s);
        }
        if (tid < 32) {
            int pb = tid >> 1, ph = tid & 1;
            *(float4*)((float*)(smem + O_XF) + pb * 16 + 4 * ph) = px;
            uint2 p2; p2.x = pack2(px.x, px.y); p2.y = pack2(px.z, px.w);
            *(uint2*)(smem + O_XB + pb * 80 + ph * 8) = p2;
            if (t + 1 < NT)
                px = *(const float4*)(feat + ((size_t)(b0 + pb) * NT + (t + 1)) * 8 + 4 * ph);
        }
        // all waves: recurrent parts Whh0*h0_prev, Whh1*h1_prev (prev-step data)
        f32x4 acc0 = {bias0.x, bias0.y, bias0.z, bias0.w};
        f32x4 acc1 = {bias1.x, bias1.y, bias1.z, bias1.w};
        {
            f16x8 h0a = *(const f16x8*)(bufP + cb * 272 + q * 16);
            f16x8 h0b = *(const f16x8*)(bufP + cb * 272 + 64 + q * 16);
            f16x8 h1a = *(const f16x8*)(bufP + cb * 272 + 128 + q * 16);
            f16x8 h1b = *(const f16x8*)(bufP + cb * 272 + 192 + q * 16);
            acc0 = __builtin_amdgcn_mfma_f32_16x16x32_f16(wl0_1, h0a, acc0, 0, 0, 0);
            acc1 = __builtin_amdgcn_mfma_f32_16x16x32_f16(wl1_2, h1a, acc1, 0, 0, 0);
            acc0 = __builtin_amdgcn_mfma_f32_16x16x32_f16(wl0_2, h0b, acc0, 0, 0, 0);
            acc1 = __builtin_amdgcn_mfma_f32_16x16x32_f16(wl1_3, h1b, acc1, 0, 0, 0);
        }
        __syncthreads();   // A

        // ---- P1: VSN hidden = relu(W1 x + b1); waves 0..3 ----
        if (w < 4) {
            f16x8 b = *(const f16x8*)(smem + O_XB + cb * 80 + q * 16);
            f32x4 acc = {b1f.x, b1f.y, b1f.z, b1f.w};
            acc = __builtin_amdgcn_mfma_f32_16x16x32_f16(wv1, b, acc, 0, 0, 0);
            int j2b = 16 * w + 4 * q;
            *(uint*)(smem + O_HID + cb * 144 + j2b * 2)     = pack2(fmaxf(acc[0], 0.f), fmaxf(acc[1], 0.f));
            *(uint*)(smem + O_HID + cb * 144 + j2b * 2 + 4) = pack2(fmaxf(acc[2], 0.f), fmaxf(acc[3], 0.f));
        }
        __syncthreads();   // B

        // ---- P2: VSN2 + softmax + x~ ; wave 4 only ----
        if (w == 4) {
            f16x8 h0 = *(const f16x8*)(smem + O_HID + cb * 144 + q * 16);
            f16x8 h1 = *(const f16x8*)(smem + O_HID + cb * 144 + 64 + q * 16);
            f32x4 aA = {b2f.x, b2f.y, b2f.z, b2f.w};
            f32x4 aB = {0.f, 0.f, 0.f, 0.f};
            aA = __builtin_amdgcn_mfma_f32_16x16x32_f16(wv2_0, h0, aA, 0, 0, 0);
            aB = __builtin_amdgcn_mfma_f32_16x16x32_f16(wv2_1, h1, aB, 0, 0, 0);
            float l0 = aA[0] + aB[0], l1 = aA[1] + aB[1];
            float l2 = aA[2] + aB[2], l3 = aA[3] + aB[3];
            float mx = fmaxf(fmaxf(l0, l1), fmaxf(l2, l3));
            mx = fmaxf(mx, __shfl_xor(mx, 16, 64));
            mx = fmaxf(mx, __shfl_xor(mx, 32, 64));
            float e0 = fexp2(1.44269504f * (l0 - mx));
            float e1 = fexp2(1.44269504f * (l1 - mx));
            float e2 = fexp2(1.44269504f * (l2 - mx));
            float e3 = fexp2(1.44269504f * (l3 - mx));
            float sm = e0 + e1 + e2 + e3;
            sm += __shfl_xor(sm, 16, 64);
            sm += __shfl_xor(sm, 32, 64);
            float inv = frcp(sm);
            const float* xf = (const float*)(smem + O_XF) + cb * 16 + 4 * q;
            float v0 = xf[0] * e0 * inv;
            float v1 = xf[1] * e1 * inv;
            float v2 = xf[2] * e2 * inv;
            float v3 = xf[3] * e3 * inv;
            *(uint*)(smem + O_XS + cb * 80 + 8 * q)     = pack2(v0, v1);
            *(uint*)(smem + O_XS + cb * 80 + 8 * q + 4) = pack2(v2, v3);
        }
        __syncthreads();   // C

        // ---- P3: LSTM0 finish: 1 MFMA + gates ----
        {
            f16x8 bx = *(const f16x8*)(smem + O_XS + cb * 80 + q * 16);
            acc0 = __builtin_amdgcn_mfma_f32_16x16x32_f16(wl0_0, bx, acc0, 0, 0, 0);
            float ii = sigm(acc0[0]), ff = sigm(acc0[1]);
            float gg = tanh_(acc0[2]), oo = sigm(acc0[3]);
            c0 = ff * c0 + ii * gg;
            float h0v = oo * tanh_(c0);
            *(unsigned short*)(bufC + cb * 272 + (4 * w + q) * 2) = f16b(h0v);
        }
        __syncthreads();   // D

        // ---- P4: LSTM1 finish: 2 MFMA + gates + delta partial ----
        {
            f16x8 bb0 = *(const f16x8*)(bufC + cb * 272 + q * 16);
            f16x8 bb1 = *(const f16x8*)(bufC + cb * 272 + 64 + q * 16);
            acc1 = __builtin_amdgcn_mfma_f32_16x16x32_f16(wl1_0, bb0, acc1, 0, 0, 0);
            acc1 = __builtin_amdgcn_mfma_f32_16x16x32_f16(wl1_1, bb1, acc1, 0, 0, 0);
            float ii = sigm(acc1[0]), ff = sigm(acc1[1]);
            float gg = tanh_(acc1[2]), oo = sigm(acc1[3]);
            c1 = ff * c1 + ii * gg;
            float h1v = oo * tanh_(c1);
            *(unsigned short*)(bufC + cb * 272 + 128 + (4 * w + q) * 2) = f16b(h1v);
            float p = woj * h1v;
            p += __shfl_xor(p, 16, 64);
            p += __shfl_xor(p, 32, 64);
            if (q == 0) ((float*)(smem + O_WP))[cb * 20 + w] = p;
        }
        __syncthreads();   // E
    }

    // ---- epilogue: delta for t = 255 ----
    if (tid < 16) {
        const float* wp = (const float*)(smem + O_WP) + tid * 20;
        float4 s0 = *(const float4*)(wp);
        float4 s1 = *(const float4*)(wp + 4);
        float4 s2 = *(const float4*)(wp + 8);
        float4 s3 = *(const float4*)(wp + 12);
        float s = bov + s0.x + s0.y + s0.z + s0.w + s1.x + s1.y + s1.z + s1.w
                + s2.x + s2.y + s2.z + s2.w + s3.x + s3.y + s3.z + s3.w;
        out[(size_t)(b0 + tid) * NT + (NT - 1)] = s;
    }
}

extern "C" void kernel_launch(void* const* d_in, const int* in_sizes, int n_in,
                              void* d_out, int out_size, void* d_ws, size_t ws_size,
                              hipStream_t stream) {
    const float* feat = (const float*)d_in[0];
    const float* W1   = (const float*)d_in[1];
    const float* b1   = (const float*)d_in[2];
    const float* W2   = (const float*)d_in[3];
    const float* b2   = (const float*)d_in[4];
    const float* Wih0 = (const float*)d_in[5];
    const float* Whh0 = (const float*)d_in[6];
    const float* bih0 = (const float*)d_in[7];
    const float* bhh0 = (const float*)d_in[8];
    const float* Wih1 = (const float*)d_in[9];
    const float* Whh1 = (const float*)d_in[10];
    const float* bih1 = (const float*)d_in[11];
    const float* bhh1 = (const float*)d_in[12];
    const float* Wo   = (const float*)d_in[13];
    const float* bo   = (const float*)d_in[14];
    uint* ws   = (uint*)d_ws;
    float* out = (float*)d_out;

    hipLaunchKernelGGL(prep_kernel, dim3(40), dim3(1024), 0, stream,
                       W1, b1, W2, b2, Wih0, Whh0, bih0, bhh0,
                       Wih1, Whh1, bih1, bhh1, ws);
    hipLaunchKernelGGL(tft_main, dim3(256), dim3(1024), 0, stream,
                       feat, Wo, bo, ws, out);
}